// Round 7
// baseline (79.512 us; speedup 1.0000x reference)
//
#include <hip/hip_runtime.h>
#include <math.h>

#define NPTS 4096
#define NB 8
#define NQTOT (2*NB*NPTS)   // 65536 query slots (both directions)
#define EPSF 1e-12f
#define NCHUNK 16
#define CCH 256             // candidates per chunk (proven)
#define QPT 4               // queries per thread (R5 geometry)
#define RBLK 64             // reduce blocks

typedef float f32x2 __attribute__((ext_vector_type(2)));

// d = {fma(a.lo, b.lo, c.lo), fma(a.hi, b.lo, c.lo)}  (b word0, c word0 broadcast)
static __device__ __forceinline__ f32x2 pk_fma_bx(f32x2 a, f32x2 b, f32x2 c){
    f32x2 d;
    asm("v_pk_fma_f32 %0, %1, %2, %3 op_sel:[0,0,0] op_sel_hi:[1,0,0]"
        : "=v"(d) : "v"(a), "v"(b), "v"(c));
    return d;
}
// d = {fma(a.lo, b.hi, c.lo), fma(a.hi, b.hi, c.hi)}  (b word1 broadcast, c packed)
static __device__ __forceinline__ f32x2 pk_fma_by(f32x2 a, f32x2 b, f32x2 c){
    f32x2 d;
    asm("v_pk_fma_f32 %0, %1, %2, %3 op_sel:[0,1,0] op_sel_hi:[1,1,1]"
        : "=v"(d) : "v"(a), "v"(b), "v"(c));
    return d;
}
static __device__ __forceinline__ float fmin3(float a, float b, float c){
    float d;
    asm("v_min3_f32 %0, %1, %2, %3" : "=v"(d) : "v"(a), "v"(b), "v"(c));
    return d;
}

static __device__ __forceinline__ void project_pt(const float* __restrict__ p3,
                                                  const float* __restrict__ Pb,
                                                  float& ix, float& iy){
    float x = p3[0], y = p3[1], z = p3[2];
    float px = fmaf(Pb[0],x, fmaf(Pb[1],y, fmaf(Pb[2],z,  Pb[3])));
    float py = fmaf(Pb[4],x, fmaf(Pb[5],y, fmaf(Pb[6],z,  Pb[7])));
    float pz = fmaf(Pb[8],x, fmaf(Pb[9],y, fmaf(Pb[10],z, Pb[11])));
    ix = px / pz;
    iy = py / pz;
}

// Identical to R6's chamfer. PROBE ROUND: launched 4x back-to-back with
// identical arguments (same writes -> deterministic); dur_us delta vs R6
// gives the per-dispatch cost directly.
__global__ __launch_bounds__(256) void chamfer_fused(
        const float* __restrict__ pred, const float* __restrict__ gt,
        const float* __restrict__ P, float* __restrict__ minpart,
        unsigned* __restrict__ counter){
    __shared__ float4 cand[CCH];   // {-2x, -2y, |c|^2, 0}
    int bid   = blockIdx.x;
    int chunk = bid & 15;
    int qq    = (bid >> 4) & 3;
    int b     = (bid >> 6) & 7;
    int dir   = (bid >> 9) & 1;
    int t = threadIdx.x;

    if (bid == 0 && t == 0) *counter = 0;

    const float* Pb   = P + b * 12;
    const float* qsrc = dir ? pred : gt;
    const float* csrc = dir ? gt : pred;

    // project this block's candidate chunk into LDS
    {
        const float* p3 = csrc + (size_t)(b*NPTS + chunk*CCH + t) * 3;
        float cx, cy; project_pt(p3, Pb, cx, cy);
        cand[t] = make_float4(-2.0f*cx, -2.0f*cy, fmaf(cx,cx, cy*cy), 0.0f);
    }

    // project this thread's 4 queries (packed in pairs for pk_fma)
    f32x2 axp[QPT/2], ayp[QPT/2];
    float a2[QPT];
    #pragma unroll
    for (int q = 0; q < QPT; ++q){
        int qi = qq*1024 + q*256 + t;
        const float* p3 = qsrc + (size_t)(b*NPTS + qi) * 3;
        float ix, iy; project_pt(p3, Pb, ix, iy);
        axp[q>>1][q&1] = ix;
        ayp[q>>1][q&1] = iy;
        a2[q] = fmaf(ix,ix, iy*iy);
    }
    float mn[QPT];
    #pragma unroll
    for (int q = 0; q < QPT; ++q) mn[q] = 3.4e38f;

    __syncthreads();

    #pragma unroll 4
    for (int ci = 0; ci < CCH; ci += 2){
        float4 cd0 = cand[ci];
        float4 cd1 = cand[ci+1];
        f32x2 c0lo = {cd0.x, cd0.y}, c0hi = {cd0.z, cd0.w};
        f32x2 c1lo = {cd1.x, cd1.y}, c1hi = {cd1.z, cd1.w};
        #pragma unroll
        for (int p = 0; p < QPT/2; ++p){
            f32x2 t0 = pk_fma_bx(axp[p], c0lo, c0hi);
            t0 = pk_fma_by(ayp[p], c0lo, t0);
            f32x2 t1 = pk_fma_bx(axp[p], c1lo, c1hi);
            t1 = pk_fma_by(ayp[p], c1lo, t1);
            mn[2*p]   = fmin3(t0.x, t1.x, mn[2*p]);
            mn[2*p+1] = fmin3(t0.y, t1.y, mn[2*p+1]);
        }
    }

    int gq = dir*(NB*NPTS) + b*NPTS + qq*1024 + t;
    #pragma unroll
    for (int q = 0; q < QPT; ++q){
        minpart[(size_t)chunk*NQTOT + gq + q*256] = mn[q] + a2[q];
    }
}

// 64 blocks x 1024 threads: 16-way chunk min + sqrt + block tree sum;
// last block to arrive tree-sums the 64 partials (fixed order -> deterministic).
__global__ __launch_bounds__(1024) void reduce_all(
        const float* __restrict__ minpart, float* __restrict__ partials,
        unsigned* __restrict__ counter, float* __restrict__ out){
    __shared__ float sm[1024];
    __shared__ int last;
    int t = threadIdx.x;
    int i = blockIdx.x * 1024 + t;   // 64*1024 = 65536 queries
    float m0 = minpart[i];
    #pragma unroll
    for (int c = 1; c < NCHUNK; ++c) m0 = fminf(m0, minpart[(size_t)c*NQTOT + i]);
    sm[t] = sqrtf(fmaxf(m0, EPSF));
    __syncthreads();
    #pragma unroll
    for (int o = 512; o > 0; o >>= 1){
        if (t < o) sm[t] += sm[t + o];
        __syncthreads();
    }
    if (t == 0){
        __hip_atomic_store(&partials[blockIdx.x], sm[0],
                           __ATOMIC_RELEASE, __HIP_MEMORY_SCOPE_AGENT);
        unsigned prev = __hip_atomic_fetch_add(counter, 1u,
                           __ATOMIC_ACQ_REL, __HIP_MEMORY_SCOPE_AGENT);
        last = (prev == RBLK - 1);
    }
    __syncthreads();
    if (!last) return;

    if (t < RBLK){
        sm[t] = __hip_atomic_load(&partials[t],
                    __ATOMIC_ACQUIRE, __HIP_MEMORY_SCOPE_AGENT);
    }
    __syncthreads();
    #pragma unroll
    for (int o = RBLK/2; o > 0; o >>= 1){
        if (t < o) sm[t] += sm[t + o];
        __syncthreads();
    }
    if (t == 0) out[0] = sm[0] * (1.0f / 32768.0f);
}

extern "C" void kernel_launch(void* const* d_in, const int* in_sizes, int n_in,
                              void* d_out, int out_size, void* d_ws, size_t ws_size,
                              hipStream_t stream) {
    const float* pred = (const float*)d_in[0];
    const float* gt   = (const float*)d_in[1];
    const float* P    = (const float*)d_in[2];
    float* out = (float*)d_out;

    const size_t MINPART_BYTES = (size_t)NCHUNK * NQTOT * 4;   // 4 MB
    float*    minpart  = (float*)d_ws;
    float*    partials = (float*)((char*)d_ws + MINPART_BYTES);          // 64 floats
    unsigned* counter  = (unsigned*)((char*)d_ws + MINPART_BYTES + 4096);

    // PROBE: 4 identical chamfer launches (same writes, deterministic).
    // dur(R7) - dur(R6) = 3 * (chamfer + gap).
    chamfer_fused<<<1024, 256, 0, stream>>>(pred, gt, P, minpart, counter);
    chamfer_fused<<<1024, 256, 0, stream>>>(pred, gt, P, minpart, counter);
    chamfer_fused<<<1024, 256, 0, stream>>>(pred, gt, P, minpart, counter);
    chamfer_fused<<<1024, 256, 0, stream>>>(pred, gt, P, minpart, counter);
    reduce_all<<<RBLK, 1024, 0, stream>>>(minpart, partials, counter, out);
}

// Round 8
// 32.768 us; speedup vs baseline: 2.4265x; 2.4265x over previous
//
#include <hip/hip_runtime.h>
#include <math.h>

#define NPTS 4096
#define NB 8
#define NQTOT (2*NB*NPTS)   // 65536 query slots (both directions)
#define EPSF 1e-12f
#define NCHUNK 16
#define CCH 256             // candidates per chunk
#define QPT 8               // queries per thread (R2-proven; halves wave count)
#define RBLK 256            // reduce blocks (all CUs)

typedef float f32x2 __attribute__((ext_vector_type(2)));

// d.lo = fma(a.lo, b.w0, c.w0); d.hi = fma(a.hi, b.w0, c.w0)
static __device__ __forceinline__ f32x2 pk_fma_bx_c0(f32x2 a, f32x2 b, f32x2 c){
    f32x2 d;
    asm("v_pk_fma_f32 %0, %1, %2, %3 op_sel:[0,0,0] op_sel_hi:[1,0,0]"
        : "=v"(d) : "v"(a), "v"(b), "v"(c));
    return d;
}
// d.lo = fma(a.lo, b.w0, c.w1); d.hi = fma(a.hi, b.w0, c.w1)
static __device__ __forceinline__ f32x2 pk_fma_bx_c1(f32x2 a, f32x2 b, f32x2 c){
    f32x2 d;
    asm("v_pk_fma_f32 %0, %1, %2, %3 op_sel:[0,0,1] op_sel_hi:[1,0,1]"
        : "=v"(d) : "v"(a), "v"(b), "v"(c));
    return d;
}
// d.lo = fma(a.lo, b.w1, c.lo); d.hi = fma(a.hi, b.w1, c.hi)   (c packed)
static __device__ __forceinline__ f32x2 pk_fma_by(f32x2 a, f32x2 b, f32x2 c){
    f32x2 d;
    asm("v_pk_fma_f32 %0, %1, %2, %3 op_sel:[0,1,0] op_sel_hi:[1,1,1]"
        : "=v"(d) : "v"(a), "v"(b), "v"(c));
    return d;
}
static __device__ __forceinline__ float fmin3(float a, float b, float c){
    float d;
    asm("v_min3_f32 %0, %1, %2, %3" : "=v"(d) : "v"(a), "v"(b), "v"(c));
    return d;
}

static __device__ __forceinline__ void project_pt(const float* __restrict__ p3,
                                                  const float* __restrict__ Pb,
                                                  float& ix, float& iy){
    float x = p3[0], y = p3[1], z = p3[2];
    float px = fmaf(Pb[0],x, fmaf(Pb[1],y, fmaf(Pb[2],z,  Pb[3])));
    float py = fmaf(Pb[4],x, fmaf(Pb[5],y, fmaf(Pb[6],z,  Pb[7])));
    float pz = fmaf(Pb[8],x, fmaf(Pb[9],y, fmaf(Pb[10],z, Pb[11])));
    ix = px / pz;
    iy = py / pz;
}

// 512 blocks = 2 dirs x 8 batches x 2 query-halves x 16 candidate chunks.
// Candidate chunk in LDS as split arrays: xy-pairs (-2x,-2y) + z (|c|^2):
// 3 broadcast ds_read_b128 per 4 candidates (vs 4 for AoS float4).
__global__ __launch_bounds__(256) void chamfer_fused(
        const float* __restrict__ pred, const float* __restrict__ gt,
        const float* __restrict__ P, float* __restrict__ minpart,
        unsigned* __restrict__ counter){
    __shared__ __align__(16) float2 sxy[CCH];   // (-2x, -2y) per candidate
    __shared__ __align__(16) float  sz [CCH];   // |c|^2 per candidate
    int bid   = blockIdx.x;
    int chunk = bid & 15;
    int qhalf = (bid >> 4) & 1;
    int b     = (bid >> 5) & 7;
    int dir   = (bid >> 8) & 1;
    int t = threadIdx.x;

    if (bid == 0 && t == 0) *counter = 0;

    const float* Pb   = P + b * 12;
    const float* qsrc = dir ? pred : gt;
    const float* csrc = dir ? gt : pred;

    // project this block's candidate chunk into LDS
    {
        const float* p3 = csrc + (size_t)(b*NPTS + chunk*CCH + t) * 3;
        float cx, cy; project_pt(p3, Pb, cx, cy);
        sxy[t] = make_float2(-2.0f*cx, -2.0f*cy);
        sz[t]  = fmaf(cx,cx, cy*cy);
    }

    // project this thread's 8 queries (packed in pairs for pk_fma)
    f32x2 axp[QPT/2], ayp[QPT/2];
    float a2[QPT];
    #pragma unroll
    for (int q = 0; q < QPT; ++q){
        int qi = qhalf*2048 + q*256 + t;
        const float* p3 = qsrc + (size_t)(b*NPTS + qi) * 3;
        float ix, iy; project_pt(p3, Pb, ix, iy);
        axp[q>>1][q&1] = ix;
        ayp[q>>1][q&1] = iy;
        a2[q] = fmaf(ix,ix, iy*iy);
    }
    float mn[QPT];
    #pragma unroll
    for (int q = 0; q < QPT; ++q) mn[q] = 3.4e38f;

    __syncthreads();

    const float4* sxy4 = (const float4*)sxy;   // 2 candidates per entry
    const float4* sz4  = (const float4*)sz;    // 4 candidates per entry

    #pragma unroll 2
    for (int c4 = 0; c4 < CCH/4; ++c4){
        float4 xy01 = sxy4[2*c4];
        float4 xy23 = sxy4[2*c4 + 1];
        float4 zq   = sz4[c4];
        f32x2 b0 = {xy01.x, xy01.y}, b1 = {xy01.z, xy01.w};
        f32x2 b2 = {xy23.x, xy23.y}, b3 = {xy23.z, xy23.w};
        f32x2 z01 = {zq.x, zq.y},   z23 = {zq.z, zq.w};
        #pragma unroll
        for (int p = 0; p < QPT/2; ++p){
            f32x2 t0 = pk_fma_by(ayp[p], b0, pk_fma_bx_c0(axp[p], b0, z01));
            f32x2 t1 = pk_fma_by(ayp[p], b1, pk_fma_bx_c1(axp[p], b1, z01));
            f32x2 t2 = pk_fma_by(ayp[p], b2, pk_fma_bx_c0(axp[p], b2, z23));
            f32x2 t3 = pk_fma_by(ayp[p], b3, pk_fma_bx_c1(axp[p], b3, z23));
            mn[2*p]   = fmin3(t0.x, t1.x, mn[2*p]);
            mn[2*p]   = fmin3(t2.x, t3.x, mn[2*p]);
            mn[2*p+1] = fmin3(t0.y, t1.y, mn[2*p+1]);
            mn[2*p+1] = fmin3(t2.y, t3.y, mn[2*p+1]);
        }
    }

    int gq = dir*(NB*NPTS) + b*NPTS + qhalf*2048 + t;
    #pragma unroll
    for (int q = 0; q < QPT; ++q){
        minpart[(size_t)chunk*NQTOT + gq + q*256] = mn[q] + a2[q];
    }
}

// 256 blocks x 256 threads (all CUs): 16-way chunk min + sqrt + block tree sum;
// last block to arrive tree-sums the 256 partials (fixed order -> deterministic).
__global__ __launch_bounds__(256) void reduce_all(
        const float* __restrict__ minpart, float* __restrict__ partials,
        unsigned* __restrict__ counter, float* __restrict__ out){
    __shared__ float sm[256];
    __shared__ int last;
    int t = threadIdx.x;
    int i = blockIdx.x * 256 + t;   // 256*256 = 65536 queries
    float m0 = minpart[i];
    #pragma unroll
    for (int c = 1; c < NCHUNK; ++c) m0 = fminf(m0, minpart[(size_t)c*NQTOT + i]);
    sm[t] = sqrtf(fmaxf(m0, EPSF));
    __syncthreads();
    #pragma unroll
    for (int o = 128; o > 0; o >>= 1){
        if (t < o) sm[t] += sm[t + o];
        __syncthreads();
    }
    if (t == 0){
        __hip_atomic_store(&partials[blockIdx.x], sm[0],
                           __ATOMIC_RELEASE, __HIP_MEMORY_SCOPE_AGENT);
        unsigned prev = __hip_atomic_fetch_add(counter, 1u,
                           __ATOMIC_ACQ_REL, __HIP_MEMORY_SCOPE_AGENT);
        last = (prev == RBLK - 1);
    }
    __syncthreads();
    if (!last) return;

    sm[t] = __hip_atomic_load(&partials[t],
                __ATOMIC_ACQUIRE, __HIP_MEMORY_SCOPE_AGENT);
    __syncthreads();
    #pragma unroll
    for (int o = 128; o > 0; o >>= 1){
        if (t < o) sm[t] += sm[t + o];
        __syncthreads();
    }
    if (t == 0) out[0] = sm[0] * (1.0f / 32768.0f);
}

extern "C" void kernel_launch(void* const* d_in, const int* in_sizes, int n_in,
                              void* d_out, int out_size, void* d_ws, size_t ws_size,
                              hipStream_t stream) {
    const float* pred = (const float*)d_in[0];
    const float* gt   = (const float*)d_in[1];
    const float* P    = (const float*)d_in[2];
    float* out = (float*)d_out;

    const size_t MINPART_BYTES = (size_t)NCHUNK * NQTOT * 4;   // 4 MB
    float*    minpart  = (float*)d_ws;
    float*    partials = (float*)((char*)d_ws + MINPART_BYTES);          // 256 floats
    unsigned* counter  = (unsigned*)((char*)d_ws + MINPART_BYTES + 4096);

    chamfer_fused<<<512, 256, 0, stream>>>(pred, gt, P, minpart, counter);
    reduce_all<<<RBLK, 256, 0, stream>>>(minpart, partials, counter, out);
}

// Round 9
// 28.228 us; speedup vs baseline: 2.8168x; 1.1609x over previous
//
#include <hip/hip_runtime.h>
#include <math.h>

#define NPTS 4096
#define NB 8
#define NQTOT (2*NB*NPTS)   // 65536 query slots (both directions)
#define EPSF 1e-12f
#define NCHUNK 16
#define CCH 256             // candidates per chunk
#define QPT 8               // queries per thread

static __device__ __forceinline__ float fmin3(float a, float b, float c){
    float d;
    asm("v_min3_f32 %0, %1, %2, %3" : "=v"(d) : "v"(a), "v"(b), "v"(c));
    return d;
}

static __device__ __forceinline__ void project_pt(const float* __restrict__ p3,
                                                  const float* __restrict__ Pb,
                                                  float& ix, float& iy){
    float x = p3[0], y = p3[1], z = p3[2];
    float px = fmaf(Pb[0],x, fmaf(Pb[1],y, fmaf(Pb[2],z,  Pb[3])));
    float py = fmaf(Pb[4],x, fmaf(Pb[5],y, fmaf(Pb[6],z,  Pb[7])));
    float pz = fmaf(Pb[8],x, fmaf(Pb[9],y, fmaf(Pb[10],z, Pb[11])));
    ix = px / pz;
    iy = py / pz;
}

// 512 blocks = 2 dirs x 8 batches x 2 query-halves x 16 candidate chunks.
// SCALAR inner loop: per 2 candidates per query = 4 v_fma_f32 + 1 v_min3_f32
// (2.5 VALU/pair). pk_fma removed — measured quarter-rate on CDNA4 (R2-R8).
__global__ __launch_bounds__(256) void chamfer_fused(
        const float* __restrict__ pred, const float* __restrict__ gt,
        const float* __restrict__ P, float* __restrict__ minpart){
    __shared__ float4 cand[CCH];   // {-2x, -2y, |c|^2, 0}
    int bid   = blockIdx.x;
    int chunk = bid & 15;
    int qhalf = (bid >> 4) & 1;
    int b     = (bid >> 5) & 7;
    int dir   = (bid >> 8) & 1;
    int t = threadIdx.x;

    const float* Pb   = P + b * 12;
    const float* qsrc = dir ? pred : gt;
    const float* csrc = dir ? gt : pred;

    // project this block's candidate chunk into LDS
    {
        const float* p3 = csrc + (size_t)(b*NPTS + chunk*CCH + t) * 3;
        float cx, cy; project_pt(p3, Pb, cx, cy);
        cand[t] = make_float4(-2.0f*cx, -2.0f*cy, fmaf(cx,cx, cy*cy), 0.0f);
    }

    // project this thread's 8 queries
    float ax[QPT], ay[QPT], a2[QPT], mn[QPT];
    #pragma unroll
    for (int q = 0; q < QPT; ++q){
        int qi = qhalf*2048 + q*256 + t;
        const float* p3 = qsrc + (size_t)(b*NPTS + qi) * 3;
        float ix, iy; project_pt(p3, Pb, ix, iy);
        ax[q] = ix; ay[q] = iy;
        a2[q] = fmaf(ix,ix, iy*iy);
        mn[q] = 3.4e38f;
    }

    __syncthreads();

    #pragma unroll 4
    for (int ci = 0; ci < CCH; ci += 2){
        float4 cd0 = cand[ci];
        float4 cd1 = cand[ci+1];
        #pragma unroll
        for (int q = 0; q < QPT; ++q){
            float t0 = fmaf(ay[q], cd0.y, fmaf(ax[q], cd0.x, cd0.z));
            float t1 = fmaf(ay[q], cd1.y, fmaf(ax[q], cd1.x, cd1.z));
            mn[q] = fmin3(t0, t1, mn[q]);
        }
    }

    int gq = dir*(NB*NPTS) + b*NPTS + qhalf*2048 + t;
    #pragma unroll
    for (int q = 0; q < QPT; ++q){
        minpart[(size_t)chunk*NQTOT + gq + q*256] = mn[q] + a2[q];
    }
}

// 16-way min across chunks, sqrt, per-block partial sum.  (R5-proven)
__global__ __launch_bounds__(256) void reduce_min_sum(
        const float* __restrict__ minpart, float* __restrict__ partials){
    __shared__ float sm[256];
    int t = threadIdx.x;
    int i = blockIdx.x * 256 + t;   // 256 blocks cover 65536 queries
    float m0 = minpart[i];
    #pragma unroll
    for (int c = 1; c < NCHUNK; ++c) m0 = fminf(m0, minpart[(size_t)c*NQTOT + i]);
    float s = sqrtf(fmaxf(m0, EPSF));
    sm[t] = s; __syncthreads();
    #pragma unroll
    for (int o = 128; o > 0; o >>= 1){
        if (t < o) sm[t] += sm[t + o];
        __syncthreads();
    }
    if (t == 0) partials[blockIdx.x] = sm[0];
}

__global__ void reduce_final(const float* __restrict__ partials,
                             float* __restrict__ out){
    __shared__ float sm[256];
    int t = threadIdx.x;
    sm[t] = partials[t];
    __syncthreads();
    #pragma unroll
    for (int o = 128; o > 0; o >>= 1){
        if (t < o) sm[t] += sm[t + o];
        __syncthreads();
    }
    if (t == 0) out[0] = sm[0] * (1.0f / 32768.0f);
}

extern "C" void kernel_launch(void* const* d_in, const int* in_sizes, int n_in,
                              void* d_out, int out_size, void* d_ws, size_t ws_size,
                              hipStream_t stream) {
    const float* pred = (const float*)d_in[0];
    const float* gt   = (const float*)d_in[1];
    const float* P    = (const float*)d_in[2];
    float* out = (float*)d_out;

    float* minpart  = (float*)d_ws;                                        // 4 MB
    float* partials = (float*)((char*)d_ws + (size_t)NCHUNK*NQTOT*4);      // 1 KB

    chamfer_fused<<<512, 256, 0, stream>>>(pred, gt, P, minpart);
    reduce_min_sum<<<256, 256, 0, stream>>>(minpart, partials);
    reduce_final<<<1, 256, 0, stream>>>(partials, out);
}